// Round 6
// baseline (300.160 us; speedup 1.0000x reference)
//
#include <hip/hip_runtime.h>
#include <cstdint>
#include <cstddef>

typedef unsigned short u16;
typedef __attribute__((ext_vector_type(8))) short bf16x8;   // 8 bf16 in 4 VGPRs
typedef __attribute__((ext_vector_type(8))) unsigned short u16x8;
typedef __attribute__((ext_vector_type(4))) float f32x4;

static constexpr int Bc = 2, Sc = 2048, Ec = 1024, Hc = 16, Dc = 64;

__device__ __forceinline__ float bf2f(u16 v) {
    unsigned u = ((unsigned)v) << 16;
    float f; __builtin_memcpy(&f, &u, 4); return f;
}
__device__ __forceinline__ u16 f2bf(float f) {  // round-nearest-even
    unsigned u; __builtin_memcpy(&u, &f, 4);
    u += 0x7fffu + ((u >> 16) & 1u);
    return (u16)(u >> 16);
}
__device__ __forceinline__ bf16x8 as_bf(u16x8 v) { return __builtin_bit_cast(bf16x8, v); }

// ---------------------------------------------------------------- cast x -> bf16
__global__ void cast_f32_bf16(const float* __restrict__ in, u16* __restrict__ out, int n) {
    int i = (blockIdx.x * blockDim.x + threadIdx.x) * 4;
    if (i < n) {
        float4 v = *reinterpret_cast<const float4*>(in + i);
        ushort4 o;
        o.x = f2bf(v.x); o.y = f2bf(v.y); o.z = f2bf(v.z); o.w = f2bf(v.w);
        *reinterpret_cast<ushort4*>(out + i) = o;
    }
}

// ------------------------------------------- transpose [R][C] f32 -> [C][R] bf16
__global__ void transpose_cast(const float* __restrict__ in, u16* __restrict__ out,
                               int R, int C) {
    __shared__ float tile[32][33];
    int tx = threadIdx.x, ty = threadIdx.y;
    int c0 = blockIdx.x * 32, r0 = blockIdx.y * 32;
    tile[ty][tx] = in[(size_t)(r0 + ty) * C + c0 + tx];
    __syncthreads();
    out[(size_t)(c0 + ty) * R + r0 + tx] = f2bf(tile[tx][ty]);
}

// ------------------------------------------------------------------ bf16 GEMM
// C[M][N] = A[M][K] * Bt[N][K]^T.  128x128 tile, BK=32, 4 waves, 16x16x32 MFMA.
// m97 structure: global_load_lds width-16 staging into linear (unpadded) LDS.
template <int OUT_BF16>
__global__ __launch_bounds__(256) void gemm_bt(const u16* __restrict__ A,
                                               const u16* __restrict__ Bt,
                                               void* __restrict__ Cout,
                                               int M, int N, int K) {
    constexpr int BK = 32;
    __shared__ u16 As[128][BK];
    __shared__ u16 Bs[128][BK];
    const int m0 = blockIdx.x * 128, n0 = blockIdx.y * 128;
    const int t = threadIdx.x;
    const int lane = t & 63, w = t >> 6;
    const int wr = w >> 1, wc = w & 1;
    const int l15 = lane & 15, lhi = lane >> 4;
    const int lrow = lane >> 2, lcol = (lane & 3) * 8;   // 4 lanes per 32-u16 row

    f32x4 acc[4][4] = {};

    for (int k0 = 0; k0 < K; k0 += BK) {
#pragma unroll
        for (int i = 0; i < 2; i++) {
            const u16* ap = A + (size_t)(m0 + w * 32 + i * 16 + lrow) * K + k0 + lcol;
            __builtin_amdgcn_global_load_lds(
                (const __attribute__((address_space(1))) unsigned int*)ap,
                (__attribute__((address_space(3))) unsigned int*)&As[w * 32 + i * 16][0],
                16, 0, 0);
            const u16* bp = Bt + (size_t)(n0 + w * 32 + i * 16 + lrow) * K + k0 + lcol;
            __builtin_amdgcn_global_load_lds(
                (const __attribute__((address_space(1))) unsigned int*)bp,
                (__attribute__((address_space(3))) unsigned int*)&Bs[w * 32 + i * 16][0],
                16, 0, 0);
        }
        __syncthreads();

        bf16x8 af[4], bfv[4];
#pragma unroll
        for (int i = 0; i < 4; i++)
            af[i] = as_bf(*reinterpret_cast<const u16x8*>(&As[wr * 64 + i * 16 + l15][lhi * 8]));
#pragma unroll
        for (int j = 0; j < 4; j++)
            bfv[j] = as_bf(*reinterpret_cast<const u16x8*>(&Bs[wc * 64 + j * 16 + l15][lhi * 8]));
#pragma unroll
        for (int i = 0; i < 4; i++)
#pragma unroll
            for (int j = 0; j < 4; j++)
                acc[i][j] = __builtin_amdgcn_mfma_f32_16x16x32_bf16(af[i], bfv[j], acc[i][j], 0, 0, 0);
        __syncthreads();
    }

#pragma unroll
    for (int i = 0; i < 4; i++)
#pragma unroll
        for (int j = 0; j < 4; j++)
#pragma unroll
            for (int r = 0; r < 4; r++) {
                int row = m0 + wr * 64 + i * 16 + lhi * 4 + r;
                int col = n0 + wc * 64 + j * 16 + l15;
                float v = acc[i][j][r];
                if (OUT_BF16)
                    ((u16*)Cout)[(size_t)row * N + col] = f2bf(v);
                else
                    ((float*)Cout)[(size_t)row * N + col] = v;
            }
}

// -------------------------------------------- RoPE + head pack  qkv -> Q,K
// Q gets *0.125*log2(e) so attention can use exp2 with a fixed base.
__global__ void rope_pack(const u16* __restrict__ qkv,
                          const float* __restrict__ fcos, const float* __restrict__ fsin,
                          u16* __restrict__ Qb, u16* __restrict__ Kb) {
    int g = blockIdx.x * blockDim.x + threadIdx.x;
    int dg = g & 3;
    int h = (g >> 2) & 15;
    int row = g >> 6;
    int b = row >> 11, s = row & 2047;
    const float QS = 0.18033688011f;   // 0.125 * log2(e)

    const u16* qp = qkv + (size_t)row * 3072 + h * 64 + dg * 16;
    u16x8 q0 = *reinterpret_cast<const u16x8*>(qp);
    u16x8 q1 = *reinterpret_cast<const u16x8*>(qp + 8);
    u16x8 k0 = *reinterpret_cast<const u16x8*>(qp + 1024);
    u16x8 k1 = *reinterpret_cast<const u16x8*>(qp + 1032);

    const float* cp = fcos + (size_t)s * 32 + dg * 8;
    const float* sp = fsin + (size_t)s * 32 + dg * 8;
    float cs[8], sn[8];
#pragma unroll
    for (int p = 0; p < 8; p++) { cs[p] = cp[p]; sn[p] = sp[p]; }

    u16 qi[16], ki[16], qo[16], ko[16];
#pragma unroll
    for (int j = 0; j < 8; j++) { qi[j] = q0[j]; qi[j + 8] = q1[j]; ki[j] = k0[j]; ki[j + 8] = k1[j]; }
#pragma unroll
    for (int p = 0; p < 8; p++) {
        float x0 = bf2f(qi[2 * p]), x1 = bf2f(qi[2 * p + 1]);
        qo[2 * p]     = f2bf((x0 * cs[p] - x1 * sn[p]) * QS);
        qo[2 * p + 1] = f2bf((x0 * sn[p] + x1 * cs[p]) * QS);
        float y0 = bf2f(ki[2 * p]), y1 = bf2f(ki[2 * p + 1]);
        ko[2 * p]     = f2bf(y0 * cs[p] - y1 * sn[p]);
        ko[2 * p + 1] = f2bf(y0 * sn[p] + y1 * cs[p]);
    }

    size_t dst = ((size_t)(b * 16 + h) * 2048 + s) * 64 + dg * 16;
    u16x8 qa, qb2, ka, kb2;
#pragma unroll
    for (int j = 0; j < 8; j++) { qa[j] = qo[j]; qb2[j] = qo[j + 8]; ka[j] = ko[j]; kb2[j] = ko[j + 8]; }
    *reinterpret_cast<u16x8*>(Qb + dst) = qa;
    *reinterpret_cast<u16x8*>(Qb + dst + 8) = qb2;
    *reinterpret_cast<u16x8*>(Kb + dst) = ka;
    *reinterpret_cast<u16x8*>(Kb + dst + 8) = kb2;
}

// ---------------------------------------------- V transpose: qkvb -> VT [BH][D][S]
__global__ __launch_bounds__(256) void vtrans(const u16* __restrict__ qkv,
                                              u16* __restrict__ VT) {
    __shared__ u16 tile[64][70];
    const int bh = blockIdx.y, b = bh >> 4, h = bh & 15;
    const int s0 = blockIdx.x * 64;
    const int t = threadIdx.x;
    const int si = t >> 2, dc = (t & 3) * 16;
    const u16* src = qkv + (size_t)(b * 2048 + s0 + si) * 3072 + 2048 + h * 64 + dc;
    *reinterpret_cast<u16x8*>(&tile[si][dc])     = *reinterpret_cast<const u16x8*>(src);
    *reinterpret_cast<u16x8*>(&tile[si][dc + 8]) = *reinterpret_cast<const u16x8*>(src + 8);
    __syncthreads();
    const int d = t >> 2, sc = (t & 3) * 16;
    u16x8 v0, v1;
#pragma unroll
    for (int j = 0; j < 8; j++) { v0[j] = tile[sc + j][d]; v1[j] = tile[sc + 8 + j][d]; }
    size_t dst = ((size_t)bh * 64 + d) * 2048 + s0 + sc;
    *reinterpret_cast<u16x8*>(VT + dst)     = v0;
    *reinterpret_cast<u16x8*>(VT + dst + 8) = v1;
}

// ------------------------------------------------------- flash attention (causal)
// 1024 blocks x 4 waves. Block owns adjacent chunk pair (2k, 2k+1) of 32 q-rows
// each (both have exactly k+1 KV tiles of 64 -> perfect intra-block balance).
// Waves 0/1 split chunk 2k's tiles in half; waves 2/3 split chunk 2k+1.
// Fixed-base softmax P = exp2(s - 14): partial (o, l) over disjoint KV ranges
// are associative -> merge is a plain f32 add via LDS, one __syncthreads.
// l accumulated via ones-MFMA. 4096 waves = 4/SIMD -> TLP hides load latency.
__global__ __launch_bounds__(256, 4) void attn_fwd4(const u16* __restrict__ Qb,
                                                    const u16* __restrict__ Kb,
                                                    const u16* __restrict__ VTb,
                                                    u16* __restrict__ attn_out) {
    __shared__ u16 Ps[4][32 * 70];      // per-wave P tile (stride 70: 0 conflicts)
    __shared__ float Om[2][32][64];     // per-chunk partial O (lane-permuted cols)
    __shared__ float Ol[2][32];         // per-chunk partial l

    const int t = threadIdx.x, lane = t & 63, w = t >> 6;
    const int l15 = lane & 15, lhi = lane >> 4;
    const int c = w >> 1;               // chunk slot in block (0,1)
    const int half = w & 1;             // 0: first half of KV tiles, 1: second (incl diag)

    const int id = blockIdx.x;
    const int bh = (id & 7) + 8 * ((id >> 3) & 3);   // 4 heads per XCD
    const int kk = 31 - (id >> 5);                   // heavy-first
    const int qc = 2 * kk + c;
    const int q0 = qc * 32;
    const int b = bh >> 4, h = bh & 15;
    const u16* Kp = Kb + (size_t)bh * (Sc * Dc);
    const u16* Vp = VTb + (size_t)bh * (Sc * Dc);
    u16* PsW = &Ps[w][0];

    // Q fragments in registers
    bf16x8 qf[2][2];
#pragma unroll
    for (int qa = 0; qa < 2; qa++)
#pragma unroll
        for (int kc = 0; kc < 2; kc++)
            qf[qa][kc] = as_bf(*reinterpret_cast<const u16x8*>(
                Qb + (size_t)bh * (Sc * Dc) + (size_t)(q0 + qa * 16 + l15) * 64 + kc * 32 + lhi * 8));

    u16x8 onesu;
#pragma unroll
    for (int j = 0; j < 8; j++) onesu[j] = 0x3F80;
    const bf16x8 onesf = as_bf(onesu);

    f32x4 o[2][4] = {};
    f32x4 os[2] = {};

    const int ntiles = kk + 1;                 // == qc/2 + 1 for both chunks
    const int nh = (ntiles + 1) >> 1;          // ceil split
    const int kt0 = half ? nh : 0;
    const int kt1 = half ? ntiles : nh;
    const int last = (ntiles - 1) * 64;        // diag tile t0

    for (int kt = kt0; kt < kt1; kt++) {
        const int t0 = kt * 64;

        // K fragments for this tile (direct from L2)
        bf16x8 kf[8];
#pragma unroll
        for (int cb = 0; cb < 4; cb++) {
            const u16* kp = Kp + (size_t)(t0 + cb * 16 + l15) * 64 + lhi * 8;
            kf[cb * 2 + 0] = as_bf(*reinterpret_cast<const u16x8*>(kp));
            kf[cb * 2 + 1] = as_bf(*reinterpret_cast<const u16x8*>(kp + 32));
        }
        // V^T fragments (latency hides under QK/exp phase)
        bf16x8 vf[8];
#pragma unroll
        for (int db = 0; db < 4; db++)
#pragma unroll
            for (int kc2 = 0; kc2 < 2; kc2++)
                vf[db * 2 + kc2] = as_bf(*reinterpret_cast<const u16x8*>(
                    Vp + (size_t)(db * 16 + l15) * 2048 + t0 + kc2 * 32 + lhi * 8));

        // QK^T; C-init = -14 folds the fixed softmax base
        f32x4 s[2][4];
#pragma unroll
        for (int qa = 0; qa < 2; qa++)
#pragma unroll
            for (int cb = 0; cb < 4; cb++) {
                f32x4 v = {-14.0f, -14.0f, -14.0f, -14.0f};
                v = __builtin_amdgcn_mfma_f32_16x16x32_bf16(qf[qa][0], kf[cb * 2 + 0], v, 0, 0, 0);
                v = __builtin_amdgcn_mfma_f32_16x16x32_bf16(qf[qa][1], kf[cb * 2 + 1], v, 0, 0, 0);
                s[qa][cb] = v;
            }

        if (t0 == last) {   // causal mask, diagonal tile only
#pragma unroll
            for (int qa = 0; qa < 2; qa++)
#pragma unroll
                for (int cb = 0; cb < 4; cb++) {
                    const int tg = t0 + cb * 16 + l15;
#pragma unroll
                    for (int r = 0; r < 4; r++) {
                        const int qg = q0 + qa * 16 + lhi * 4 + r;
                        if (tg > qg) s[qa][cb][r] = -1e30f;
                    }
                }
        }

        // P = exp2(s), truncated bf16 store to wave-private LDS
#pragma unroll
        for (int qa = 0; qa < 2; qa++)
#pragma unroll
            for (int cb = 0; cb < 4; cb++)
#pragma unroll
                for (int r = 0; r < 4; r++) {
                    float p = __builtin_amdgcn_exp2f(s[qa][cb][r]);
                    unsigned pb; __builtin_memcpy(&pb, &p, 4);
                    PsW[(qa * 16 + lhi * 4 + r) * 70 + cb * 16 + l15] = (u16)(pb >> 16);
                }
        asm volatile("s_waitcnt lgkmcnt(0)" ::: "memory");
        __builtin_amdgcn_sched_barrier(0);   // rule #18: keep MFMA below the waitcnt

        // PV + row-sum via ones fragment
#pragma unroll
        for (int qa = 0; qa < 2; qa++) {
            bf16x8 pf0 = as_bf(*reinterpret_cast<const u16x8*>(&PsW[(qa * 16 + l15) * 70 + lhi * 8]));
            bf16x8 pf1 = as_bf(*reinterpret_cast<const u16x8*>(&PsW[(qa * 16 + l15) * 70 + 32 + lhi * 8]));
            os[qa] = __builtin_amdgcn_mfma_f32_16x16x32_bf16(pf0, onesf, os[qa], 0, 0, 0);
            os[qa] = __builtin_amdgcn_mfma_f32_16x16x32_bf16(pf1, onesf, os[qa], 0, 0, 0);
#pragma unroll
            for (int db = 0; db < 4; db++) {
                o[qa][db] = __builtin_amdgcn_mfma_f32_16x16x32_bf16(pf0, vf[db * 2 + 0], o[qa][db], 0, 0, 0);
                o[qa][db] = __builtin_amdgcn_mfma_f32_16x16x32_bf16(pf1, vf[db * 2 + 1], o[qa][db], 0, 0, 0);
            }
        }
    }

    // ---- split-KV merge: odd waves publish partials, even waves combine + write.
    // Om cols lane-permuted (l15*4+db contiguous per lane -> b128); reader uses
    // the same (db,l15) mapping so the permutation cancels.
    if (half) {
#pragma unroll
        for (int qa = 0; qa < 2; qa++)
#pragma unroll
            for (int r = 0; r < 4; r++) {
                const int row = qa * 16 + lhi * 4 + r;
                if (l15 == 0) Ol[c][row] = os[qa][r];
                f32x4 pk;
#pragma unroll
                for (int db = 0; db < 4; db++) pk[db] = o[qa][db][r];
                *reinterpret_cast<f32x4*>(&Om[c][row][l15 * 4]) = pk;
            }
    }
    __syncthreads();
    if (!half) {
#pragma unroll
        for (int qa = 0; qa < 2; qa++)
#pragma unroll
            for (int r = 0; r < 4; r++) {
                const int row = qa * 16 + lhi * 4 + r;
                const float l = os[qa][r] + Ol[c][row];
                const float inv = 1.0f / l;
                f32x4 pk = *reinterpret_cast<const f32x4*>(&Om[c][row][l15 * 4]);
                const int qg = q0 + row;
                const size_t orow = ((size_t)(b * 2048 + qg)) * 1024 + h * 64;
#pragma unroll
                for (int db = 0; db < 4; db++)
                    attn_out[orow + db * 16 + l15] = f2bf((o[qa][db][r] + pk[db]) * inv);
            }
    }
}

// ---------------------------------------------------------------------- launch
extern "C" void kernel_launch(void* const* d_in, const int* in_sizes, int n_in,
                              void* d_out, int out_size, void* d_ws, size_t ws_size,
                              hipStream_t stream) {
    const float* x     = (const float*)d_in[0];
    const float* w_qkv = (const float*)d_in[1];
    const float* w_out = (const float*)d_in[2];
    const float* fcos  = (const float*)d_in[3];
    const float* fsin  = (const float*)d_in[4];
    float* out = (float*)d_out;

    char* ws = (char*)d_ws;
    u16* xb    = (u16*)(ws);                       //  8,388,608 B
    u16* wqkvT = (u16*)(ws + 8388608);             //  6,291,456 B
    u16* woutT = (u16*)(ws + 14680064);            //  2,097,152 B
    u16* qkvb  = (u16*)(ws + 16777216);            // 25,165,824 B
    u16* Qb    = (u16*)(ws + 41943040);            //  8,388,608 B
    u16* Kb    = (u16*)(ws + 50331648);            //  8,388,608 B
    u16* VTb   = (u16*)(ws + 58720256);            //  8,388,608 B  (V transposed)
    u16* attnb = (u16*)(ws + 67108864);            //  8,388,608 B

    cast_f32_bf16<<<4096, 256, 0, stream>>>(x, xb, Bc * Sc * Ec);
    transpose_cast<<<dim3(96, 32), dim3(32, 32), 0, stream>>>(w_qkv, wqkvT, 1024, 3072);
    transpose_cast<<<dim3(32, 32), dim3(32, 32), 0, stream>>>(w_out, woutT, 1024, 1024);
    gemm_bt<1><<<dim3(32, 24), 256, 0, stream>>>(xb, wqkvT, qkvb, 4096, 3072, 1024);
    rope_pack<<<1024, 256, 0, stream>>>(qkvb, fcos, fsin, Qb, Kb);
    vtrans<<<dim3(32, 32), 256, 0, stream>>>(qkvb, VTb);
    attn_fwd4<<<1024, 256, 0, stream>>>(Qb, Kb, VTb, attnb);
    gemm_bt<0><<<dim3(32, 8), 256, 0, stream>>>(attnb, woutT, out, 4096, 1024, 1024);
}

// Round 7
// 230.161 us; speedup vs baseline: 1.3041x; 1.3041x over previous
//
#include <hip/hip_runtime.h>
#include <cstdint>
#include <cstddef>

typedef unsigned short u16;
typedef __attribute__((ext_vector_type(8))) short bf16x8;   // 8 bf16 in 4 VGPRs
typedef __attribute__((ext_vector_type(8))) unsigned short u16x8;
typedef __attribute__((ext_vector_type(4))) float f32x4;

static constexpr int Bc = 2, Sc = 2048, Ec = 1024, Hc = 16, Dc = 64;

__device__ __forceinline__ float bf2f(u16 v) {
    unsigned u = ((unsigned)v) << 16;
    float f; __builtin_memcpy(&f, &u, 4); return f;
}
__device__ __forceinline__ u16 f2bf(float f) {  // round-nearest-even
    unsigned u; __builtin_memcpy(&u, &f, 4);
    u += 0x7fffu + ((u >> 16) & 1u);
    return (u16)(u >> 16);
}
__device__ __forceinline__ bf16x8 as_bf(u16x8 v) { return __builtin_bit_cast(bf16x8, v); }

// ---------------------------------------------------------------- cast x -> bf16
__global__ void cast_f32_bf16(const float* __restrict__ in, u16* __restrict__ out, int n) {
    int i = (blockIdx.x * blockDim.x + threadIdx.x) * 4;
    if (i < n) {
        float4 v = *reinterpret_cast<const float4*>(in + i);
        ushort4 o;
        o.x = f2bf(v.x); o.y = f2bf(v.y); o.z = f2bf(v.z); o.w = f2bf(v.w);
        *reinterpret_cast<ushort4*>(out + i) = o;
    }
}

// ------------------------------------------- transpose [R][C] f32 -> [C][R] bf16
__global__ void transpose_cast(const float* __restrict__ in, u16* __restrict__ out,
                               int R, int C) {
    __shared__ float tile[32][33];
    int tx = threadIdx.x, ty = threadIdx.y;
    int c0 = blockIdx.x * 32, r0 = blockIdx.y * 32;
    tile[ty][tx] = in[(size_t)(r0 + ty) * C + c0 + tx];
    __syncthreads();
    out[(size_t)(c0 + ty) * R + r0 + tx] = f2bf(tile[tx][ty]);
}

// ------------------------------------------------------------------ bf16 GEMM
// C[M][N] = A[M][K] * Bt[N][K]^T.  128x128 tile, BK=32, 4 waves, 16x16x32 MFMA.
// m97 structure: global_load_lds width-16 staging into linear (unpadded) LDS.
template <int OUT_BF16>
__global__ __launch_bounds__(256) void gemm_bt(const u16* __restrict__ A,
                                               const u16* __restrict__ Bt,
                                               void* __restrict__ Cout,
                                               int M, int N, int K) {
    constexpr int BK = 32;
    __shared__ u16 As[128][BK];
    __shared__ u16 Bs[128][BK];
    const int m0 = blockIdx.x * 128, n0 = blockIdx.y * 128;
    const int t = threadIdx.x;
    const int lane = t & 63, w = t >> 6;
    const int wr = w >> 1, wc = w & 1;
    const int l15 = lane & 15, lhi = lane >> 4;
    const int lrow = lane >> 2, lcol = (lane & 3) * 8;   // 4 lanes per 32-u16 row

    f32x4 acc[4][4] = {};

    for (int k0 = 0; k0 < K; k0 += BK) {
#pragma unroll
        for (int i = 0; i < 2; i++) {
            const u16* ap = A + (size_t)(m0 + w * 32 + i * 16 + lrow) * K + k0 + lcol;
            __builtin_amdgcn_global_load_lds(
                (const __attribute__((address_space(1))) unsigned int*)ap,
                (__attribute__((address_space(3))) unsigned int*)&As[w * 32 + i * 16][0],
                16, 0, 0);
            const u16* bp = Bt + (size_t)(n0 + w * 32 + i * 16 + lrow) * K + k0 + lcol;
            __builtin_amdgcn_global_load_lds(
                (const __attribute__((address_space(1))) unsigned int*)bp,
                (__attribute__((address_space(3))) unsigned int*)&Bs[w * 32 + i * 16][0],
                16, 0, 0);
        }
        __syncthreads();

        bf16x8 af[4], bfv[4];
#pragma unroll
        for (int i = 0; i < 4; i++)
            af[i] = as_bf(*reinterpret_cast<const u16x8*>(&As[wr * 64 + i * 16 + l15][lhi * 8]));
#pragma unroll
        for (int j = 0; j < 4; j++)
            bfv[j] = as_bf(*reinterpret_cast<const u16x8*>(&Bs[wc * 64 + j * 16 + l15][lhi * 8]));
#pragma unroll
        for (int i = 0; i < 4; i++)
#pragma unroll
            for (int j = 0; j < 4; j++)
                acc[i][j] = __builtin_amdgcn_mfma_f32_16x16x32_bf16(af[i], bfv[j], acc[i][j], 0, 0, 0);
        __syncthreads();
    }

#pragma unroll
    for (int i = 0; i < 4; i++)
#pragma unroll
        for (int j = 0; j < 4; j++)
#pragma unroll
            for (int r = 0; r < 4; r++) {
                int row = m0 + wr * 64 + i * 16 + lhi * 4 + r;
                int col = n0 + wc * 64 + j * 16 + l15;
                float v = acc[i][j][r];
                if (OUT_BF16)
                    ((u16*)Cout)[(size_t)row * N + col] = f2bf(v);
                else
                    ((float*)Cout)[(size_t)row * N + col] = v;
            }
}

// -------------------------------------------- RoPE + head pack  qkv -> Q,K
// Q gets *0.125*log2(e) so attention can use exp2 with a fixed base.
__global__ void rope_pack(const u16* __restrict__ qkv,
                          const float* __restrict__ fcos, const float* __restrict__ fsin,
                          u16* __restrict__ Qb, u16* __restrict__ Kb) {
    int g = blockIdx.x * blockDim.x + threadIdx.x;
    int dg = g & 3;
    int h = (g >> 2) & 15;
    int row = g >> 6;
    int b = row >> 11, s = row & 2047;
    const float QS = 0.18033688011f;   // 0.125 * log2(e)

    const u16* qp = qkv + (size_t)row * 3072 + h * 64 + dg * 16;
    u16x8 q0 = *reinterpret_cast<const u16x8*>(qp);
    u16x8 q1 = *reinterpret_cast<const u16x8*>(qp + 8);
    u16x8 k0 = *reinterpret_cast<const u16x8*>(qp + 1024);
    u16x8 k1 = *reinterpret_cast<const u16x8*>(qp + 1032);

    const float* cp = fcos + (size_t)s * 32 + dg * 8;
    const float* sp = fsin + (size_t)s * 32 + dg * 8;
    float cs[8], sn[8];
#pragma unroll
    for (int p = 0; p < 8; p++) { cs[p] = cp[p]; sn[p] = sp[p]; }

    u16 qi[16], ki[16], qo[16], ko[16];
#pragma unroll
    for (int j = 0; j < 8; j++) { qi[j] = q0[j]; qi[j + 8] = q1[j]; ki[j] = k0[j]; ki[j + 8] = k1[j]; }
#pragma unroll
    for (int p = 0; p < 8; p++) {
        float x0 = bf2f(qi[2 * p]), x1 = bf2f(qi[2 * p + 1]);
        qo[2 * p]     = f2bf((x0 * cs[p] - x1 * sn[p]) * QS);
        qo[2 * p + 1] = f2bf((x0 * sn[p] + x1 * cs[p]) * QS);
        float y0 = bf2f(ki[2 * p]), y1 = bf2f(ki[2 * p + 1]);
        ko[2 * p]     = f2bf(y0 * cs[p] - y1 * sn[p]);
        ko[2 * p + 1] = f2bf(y0 * sn[p] + y1 * cs[p]);
    }

    size_t dst = ((size_t)(b * 16 + h) * 2048 + s) * 64 + dg * 16;
    u16x8 qa, qb2, ka, kb2;
#pragma unroll
    for (int j = 0; j < 8; j++) { qa[j] = qo[j]; qb2[j] = qo[j + 8]; ka[j] = ko[j]; kb2[j] = ko[j + 8]; }
    *reinterpret_cast<u16x8*>(Qb + dst) = qa;
    *reinterpret_cast<u16x8*>(Qb + dst + 8) = qb2;
    *reinterpret_cast<u16x8*>(Kb + dst) = ka;
    *reinterpret_cast<u16x8*>(Kb + dst + 8) = kb2;
}

// ---------------------------------------------- V transpose: qkvb -> VT [BH][D][S]
__global__ __launch_bounds__(256) void vtrans(const u16* __restrict__ qkv,
                                              u16* __restrict__ VT) {
    __shared__ u16 tile[64][70];
    const int bh = blockIdx.y, b = bh >> 4, h = bh & 15;
    const int s0 = blockIdx.x * 64;
    const int t = threadIdx.x;
    const int si = t >> 2, dc = (t & 3) * 16;
    const u16* src = qkv + (size_t)(b * 2048 + s0 + si) * 3072 + 2048 + h * 64 + dc;
    *reinterpret_cast<u16x8*>(&tile[si][dc])     = *reinterpret_cast<const u16x8*>(src);
    *reinterpret_cast<u16x8*>(&tile[si][dc + 8]) = *reinterpret_cast<const u16x8*>(src + 8);
    __syncthreads();
    const int d = t >> 2, sc = (t & 3) * 16;
    u16x8 v0, v1;
#pragma unroll
    for (int j = 0; j < 8; j++) { v0[j] = tile[sc + j][d]; v1[j] = tile[sc + 8 + j][d]; }
    size_t dst = ((size_t)bh * 64 + d) * 2048 + s0 + sc;
    *reinterpret_cast<u16x8*>(VT + dst)     = v0;
    *reinterpret_cast<u16x8*>(VT + dst + 8) = v1;
}

// ------------------------------------------------------- flash attention (causal)
// Same work decomposition as attn_fwd4 (1024 blocks x 4 waves, adjacent chunk
// pair, split-KV halves, exact f32 LDS merge, fixed-base softmax exp2(s-14),
// ones-MFMA row-sum). SPILL FIX vs fwd4 (which ran at 64 VGPR + 235 MB scratch
// writes): no min-occupancy launch bound, and K/V fragments held only 4 at a
// time (two kc passes for QK and for PV; P re-read from LDS per pass).
// Peak live set ~110 VGPR -> fits the 128-VGPR / 4-wave-per-SIMD budget.
__global__ __launch_bounds__(256) void attn_fwd5(const u16* __restrict__ Qb,
                                                 const u16* __restrict__ Kb,
                                                 const u16* __restrict__ VTb,
                                                 u16* __restrict__ attn_out) {
    __shared__ u16 Ps[4][32 * 70];      // per-wave P tile (stride 70: 0 conflicts)
    __shared__ float Om[2][32][64];     // per-chunk partial O (lane-permuted cols)
    __shared__ float Ol[2][32];         // per-chunk partial l

    const int t = threadIdx.x, lane = t & 63, w = t >> 6;
    const int l15 = lane & 15, lhi = lane >> 4;
    const int c = w >> 1;               // chunk slot in block (0,1)
    const int half = w & 1;             // 0: first half of KV tiles, 1: second (incl diag)

    const int id = blockIdx.x;
    const int bh = (id & 7) + 8 * ((id >> 3) & 3);   // 4 heads per XCD
    const int kk = 31 - (id >> 5);                   // heavy-first
    const int qc = 2 * kk + c;
    const int q0 = qc * 32;
    const int b = bh >> 4, h = bh & 15;
    const u16* Kp = Kb + (size_t)bh * (Sc * Dc);
    const u16* Vp = VTb + (size_t)bh * (Sc * Dc);
    u16* PsW = &Ps[w][0];

    // Q fragments in registers
    bf16x8 qf[2][2];
#pragma unroll
    for (int qa = 0; qa < 2; qa++)
#pragma unroll
        for (int kc = 0; kc < 2; kc++)
            qf[qa][kc] = as_bf(*reinterpret_cast<const u16x8*>(
                Qb + (size_t)bh * (Sc * Dc) + (size_t)(q0 + qa * 16 + l15) * 64 + kc * 32 + lhi * 8));

    u16x8 onesu;
#pragma unroll
    for (int j = 0; j < 8; j++) onesu[j] = 0x3F80;
    const bf16x8 onesf = as_bf(onesu);

    f32x4 o[2][4] = {};
    f32x4 os[2] = {};

    const int ntiles = kk + 1;                 // == qc/2 + 1 for both chunks
    const int nh = (ntiles + 1) >> 1;          // ceil split
    const int kt0 = half ? nh : 0;
    const int kt1 = half ? ntiles : nh;
    const int last = (ntiles - 1) * 64;        // diag tile t0

    for (int kt = kt0; kt < kt1; kt++) {
        const int t0 = kt * 64;

        f32x4 s[2][4];
        // ---- QK^T pass kc=0: only 4 K fragments live
        {
            bf16x8 kf[4];
#pragma unroll
            for (int cb = 0; cb < 4; cb++)
                kf[cb] = as_bf(*reinterpret_cast<const u16x8*>(
                    Kp + (size_t)(t0 + cb * 16 + l15) * 64 + lhi * 8));
#pragma unroll
            for (int qa = 0; qa < 2; qa++)
#pragma unroll
                for (int cb = 0; cb < 4; cb++) {
                    f32x4 v = {-14.0f, -14.0f, -14.0f, -14.0f};   // fixed softmax base
                    s[qa][cb] = __builtin_amdgcn_mfma_f32_16x16x32_bf16(qf[qa][0], kf[cb], v, 0, 0, 0);
                }
        }
        // ---- QK^T pass kc=1
        {
            bf16x8 kf[4];
#pragma unroll
            for (int cb = 0; cb < 4; cb++)
                kf[cb] = as_bf(*reinterpret_cast<const u16x8*>(
                    Kp + (size_t)(t0 + cb * 16 + l15) * 64 + 32 + lhi * 8));
#pragma unroll
            for (int qa = 0; qa < 2; qa++)
#pragma unroll
                for (int cb = 0; cb < 4; cb++)
                    s[qa][cb] = __builtin_amdgcn_mfma_f32_16x16x32_bf16(qf[qa][1], kf[cb], s[qa][cb], 0, 0, 0);
        }

        if (t0 == last) {   // causal mask, diagonal tile only
#pragma unroll
            for (int qa = 0; qa < 2; qa++)
#pragma unroll
                for (int cb = 0; cb < 4; cb++) {
                    const int tg = t0 + cb * 16 + l15;
#pragma unroll
                    for (int r = 0; r < 4; r++) {
                        const int qg = q0 + qa * 16 + lhi * 4 + r;
                        if (tg > qg) s[qa][cb][r] = -1e30f;
                    }
                }
        }

        // P = exp2(s), truncated bf16 store to wave-private LDS
#pragma unroll
        for (int qa = 0; qa < 2; qa++)
#pragma unroll
            for (int cb = 0; cb < 4; cb++)
#pragma unroll
                for (int r = 0; r < 4; r++) {
                    float p = __builtin_amdgcn_exp2f(s[qa][cb][r]);
                    unsigned pb; __builtin_memcpy(&pb, &p, 4);
                    PsW[(qa * 16 + lhi * 4 + r) * 70 + cb * 16 + l15] = (u16)(pb >> 16);
                }
        asm volatile("s_waitcnt lgkmcnt(0)" ::: "memory");
        __builtin_amdgcn_sched_barrier(0);   // rule #18: keep MFMA below the waitcnt

        // ---- PV + row-sum, two kc passes: only 4 V fragments live at a time
#pragma unroll
        for (int kc = 0; kc < 2; kc++) {
            bf16x8 vf[4];
#pragma unroll
            for (int db = 0; db < 4; db++)
                vf[db] = as_bf(*reinterpret_cast<const u16x8*>(
                    Vp + (size_t)(db * 16 + l15) * 2048 + t0 + kc * 32 + lhi * 8));
#pragma unroll
            for (int qa = 0; qa < 2; qa++) {
                bf16x8 pf = as_bf(*reinterpret_cast<const u16x8*>(
                    &PsW[(qa * 16 + l15) * 70 + kc * 32 + lhi * 8]));
                os[qa] = __builtin_amdgcn_mfma_f32_16x16x32_bf16(pf, onesf, os[qa], 0, 0, 0);
#pragma unroll
                for (int db = 0; db < 4; db++)
                    o[qa][db] = __builtin_amdgcn_mfma_f32_16x16x32_bf16(pf, vf[db], o[qa][db], 0, 0, 0);
            }
        }
    }

    // ---- split-KV merge: odd waves publish partials, even waves combine + write.
    // Om cols lane-permuted (l15*4+db contiguous per lane -> b128); reader uses
    // the same (db,l15) mapping so the permutation cancels.
    if (half) {
#pragma unroll
        for (int qa = 0; qa < 2; qa++)
#pragma unroll
            for (int r = 0; r < 4; r++) {
                const int row = qa * 16 + lhi * 4 + r;
                if (l15 == 0) Ol[c][row] = os[qa][r];
                f32x4 pk;
#pragma unroll
                for (int db = 0; db < 4; db++) pk[db] = o[qa][db][r];
                *reinterpret_cast<f32x4*>(&Om[c][row][l15 * 4]) = pk;
            }
    }
    __syncthreads();
    if (!half) {
#pragma unroll
        for (int qa = 0; qa < 2; qa++)
#pragma unroll
            for (int r = 0; r < 4; r++) {
                const int row = qa * 16 + lhi * 4 + r;
                const float l = os[qa][r] + Ol[c][row];
                const float inv = 1.0f / l;
                f32x4 pk = *reinterpret_cast<const f32x4*>(&Om[c][row][l15 * 4]);
                const int qg = q0 + row;
                const size_t orow = ((size_t)(b * 2048 + qg)) * 1024 + h * 64;
#pragma unroll
                for (int db = 0; db < 4; db++)
                    attn_out[orow + db * 16 + l15] = f2bf((o[qa][db][r] + pk[db]) * inv);
            }
    }
}

// ---------------------------------------------------------------------- launch
extern "C" void kernel_launch(void* const* d_in, const int* in_sizes, int n_in,
                              void* d_out, int out_size, void* d_ws, size_t ws_size,
                              hipStream_t stream) {
    const float* x     = (const float*)d_in[0];
    const float* w_qkv = (const float*)d_in[1];
    const float* w_out = (const float*)d_in[2];
    const float* fcos  = (const float*)d_in[3];
    const float* fsin  = (const float*)d_in[4];
    float* out = (float*)d_out;

    char* ws = (char*)d_ws;
    u16* xb    = (u16*)(ws);                       //  8,388,608 B
    u16* wqkvT = (u16*)(ws + 8388608);             //  6,291,456 B
    u16* woutT = (u16*)(ws + 14680064);            //  2,097,152 B
    u16* qkvb  = (u16*)(ws + 16777216);            // 25,165,824 B
    u16* Qb    = (u16*)(ws + 41943040);            //  8,388,608 B
    u16* Kb    = (u16*)(ws + 50331648);            //  8,388,608 B
    u16* VTb   = (u16*)(ws + 58720256);            //  8,388,608 B  (V transposed)
    u16* attnb = (u16*)(ws + 67108864);            //  8,388,608 B

    cast_f32_bf16<<<4096, 256, 0, stream>>>(x, xb, Bc * Sc * Ec);
    transpose_cast<<<dim3(96, 32), dim3(32, 32), 0, stream>>>(w_qkv, wqkvT, 1024, 3072);
    transpose_cast<<<dim3(32, 32), dim3(32, 32), 0, stream>>>(w_out, woutT, 1024, 1024);
    gemm_bt<1><<<dim3(32, 24), 256, 0, stream>>>(xb, wqkvT, qkvb, 4096, 3072, 1024);
    rope_pack<<<1024, 256, 0, stream>>>(qkvb, fcos, fsin, Qb, Kb);
    vtrans<<<dim3(32, 32), 256, 0, stream>>>(qkvb, VTb);
    attn_fwd5<<<1024, 256, 0, stream>>>(Qb, Kb, VTb, attnb);
    gemm_bt<0><<<dim3(32, 8), 256, 0, stream>>>(attnb, woutT, out, 4096, 1024, 1024);
}